// Round 25
// baseline (792.593 us; speedup 1.0000x reference)
//
#include <hip/hip_runtime.h>
#include <hip/hip_bf16.h>

#define BZ 4
#define DD 64
#define LL 16384
#define NN 8
#define BLD ((size_t)BZ*DD*LL)      // 4,194,304
#define BML ((size_t)BZ*20*LL)      // 1,310,720

typedef unsigned short ushort_t;
typedef unsigned int uint_t;

__device__ __forceinline__ float silu_(float x){ return __fdividef(x, 1.f + __expf(-x)); }
__device__ __forceinline__ float softplus_(float x){ return (x > 20.f) ? x : __logf(1.f + __expf(x)); }
__device__ __forceinline__ ushort_t f2b(float x){
  uint_t u = __float_as_uint(x);
  u = (u + 0x7FFFu + ((u >> 16) & 1u)) >> 16;
  return (ushort_t)u;
}
__device__ __forceinline__ float b2f(ushort_t h){ return __uint_as_float(((uint_t)h) << 16); }
__device__ __forceinline__ uint_t pk(float a, float b){ return (uint_t)f2b(a) | ((uint_t)f2b(b) << 16); }

// ================= fused path =================

// ---- input stage: sel = (pair, path); XB/ZB and meta stored bf16 ----
__global__ __launch_bounds__(256)
void k_in2(const float* __restrict__ s0a, const float* __restrict__ s1a,
           const float* __restrict__ s0b, const float* __restrict__ s1b,
           const float* __restrict__ lng0, const float* __restrict__ lnb0,
           const float* __restrict__ lng1, const float* __restrict__ lnb1,
           const float* __restrict__ W_in, const float* __restrict__ W_ine,
           const float* __restrict__ W_x, int i0,
           ushort_t* __restrict__ XBa, ushort_t* __restrict__ ZBa,
           ushort_t* __restrict__ XBb, ushort_t* __restrict__ ZBb,
           ushort_t* __restrict__ M00, ushort_t* __restrict__ M01,
           ushort_t* __restrict__ M10, ushort_t* __restrict__ M11)
{
  const int sel  = blockIdx.x >> 8;                // 0..3
  const int pi   = sel & 1;
  const int path = sel >> 1;
  const int pos = (blockIdx.x & 255)*256 + threadIdx.x;
  const int b = pos >> 14;
  const int l = pos & (LL-1);
  const int i = i0 + pi;

  if (path == 0){
    const float* src0 = pi ? s0b : s0a;
    float a[DD];
    #pragma unroll
    for (int ch=0; ch<DD; ++ch) a[ch] = src0[((size_t)(b*DD+ch))*LL + l];
    float m=0.f;
    #pragma unroll
    for (int k=0;k<DD;++k) m += a[k];
    m *= (1.f/DD);
    float v=0.f;
    #pragma unroll
    for (int k=0;k<DD;++k){ float d=a[k]-m; v += d*d; }
    v *= (1.f/DD);
    const float rs = rsqrtf(v + 1e-5f);
    #pragma unroll
    for (int k=0;k<DD;++k) a[k] = (a[k]-m)*rs*lng0[i*DD+k] + lnb0[i*DD+k];

    const float* Wi = W_in + (size_t)i*DD*2*DD;
    ushort_t* xrow = (pi ? XBb : XBa) + ((size_t)b*LL + l)*DD;
    ushort_t* zrow = (pi ? ZBb : ZBa) + ((size_t)b*LL + l)*DD;
    for (int g=0; g<8; ++g){
      float acc[16];
      #pragma unroll
      for (int j=0;j<16;++j) acc[j]=0.f;
      #pragma unroll
      for (int k=0;k<DD;++k){
        const float av = a[k];
        const float* wr = Wi + k*128 + g*16;
        #pragma unroll
        for (int j=0;j<16;++j) acc[j] = fmaf(av, wr[j], acc[j]);
      }
      ushort_t* drow = (g<4) ? (xrow + g*16) : (zrow + (g-4)*16);
      uint4 o0, o1;
      o0.x = pk(acc[0],acc[1]);  o0.y = pk(acc[2],acc[3]);
      o0.z = pk(acc[4],acc[5]);  o0.w = pk(acc[6],acc[7]);
      o1.x = pk(acc[8],acc[9]);  o1.y = pk(acc[10],acc[11]);
      o1.z = pk(acc[12],acc[13]);o1.w = pk(acc[14],acc[15]);
      ((uint4*)drow)[0] = o0;
      ((uint4*)drow)[1] = o1;
    }
  } else {
    const float* src1 = pi ? s1b : s1a;
    float e[DD];
    #pragma unroll
    for (int ch=0; ch<DD; ++ch) e[ch] = src1[((size_t)(b*DD+ch))*LL + l];
    float m=0.f;
    #pragma unroll
    for (int k=0;k<DD;++k) m += e[k];
    m *= (1.f/DD);
    float v=0.f;
    #pragma unroll
    for (int k=0;k<DD;++k){ float d=e[k]-m; v += d*d; }
    v *= (1.f/DD);
    const float rs = rsqrtf(v + 1e-5f);
    #pragma unroll
    for (int k=0;k<DD;++k) e[k] = (e[k]-m)*rs*lng1[i*DD+k] + lnb1[i*DD+k];

    const float* We  = W_ine + (size_t)i*DD*DD;
    const float* Wx0 = W_x + ((size_t)(i*2+0)*DD)*20;
    const float* Wx1 = W_x + ((size_t)(i*2+1)*DD)*20;
    float acc0[20], acc1[20];
    #pragma unroll
    for (int j=0;j<20;++j){ acc0[j]=0.f; acc1[j]=0.f; }
    for (int gg=0; gg<4; ++gg){
      float eeg[16];
      #pragma unroll
      for (int j=0;j<16;++j) eeg[j]=0.f;
      #pragma unroll
      for (int k=0;k<DD;++k){
        const float ev = e[k];
        const float* wr = We + k*DD + gg*16;
        #pragma unroll
        for (int j=0;j<16;++j) eeg[j] = fmaf(ev, wr[j], eeg[j]);
      }
      const float* w0 = Wx0 + (size_t)(gg*16)*20;
      const float* w1 = Wx1 + (size_t)(gg*16)*20;
      #pragma unroll
      for (int jj=0;jj<16;++jj){
        const float s = eeg[jj];
        #pragma unroll
        for (int j=0;j<20;++j){
          acc0[j] = fmaf(s, w0[jj*20+j], acc0[j]);
          acc1[j] = fmaf(s, w1[jj*20+j], acc1[j]);
        }
      }
    }
    ushort_t* mrow0 = (pi ? M10 : M00) + ((size_t)b*LL + l)*20;
    ushort_t* mrow1 = (pi ? M11 : M01) + ((size_t)b*LL + l)*20;
    #pragma unroll
    for (int q=0;q<5;++q){
      uint2 w0v, w1v;
      w0v.x = pk(acc0[4*q+0], acc0[4*q+1]);
      w0v.y = pk(acc0[4*q+2], acc0[4*q+3]);
      w1v.x = pk(acc1[4*q+0], acc1[4*q+1]);
      w1v.y = pk(acc1[4*q+2], acc1[4*q+3]);
      ((uint2*)mrow0)[q] = w0v;
      ((uint2*)mrow1)[q] = w1v;
    }
  }
}

// ---- fused 4-instance chunked scan; xb/zb/yb/meta in bf16 ----
template<int NC2, bool PASSC>
__global__ __launch_bounds__(64)
void k_scan4(const ushort_t* __restrict__ XBa, const ushort_t* __restrict__ XBb,
             const ushort_t* __restrict__ ZBa, const ushort_t* __restrict__ ZBb,
             ushort_t* __restrict__ Y0, ushort_t* __restrict__ Y1,
             ushort_t* __restrict__ Y2, ushort_t* __restrict__ Y3,
             const ushort_t* __restrict__ M00, const ushort_t* __restrict__ M01,
             const ushort_t* __restrict__ M10, const ushort_t* __restrict__ M11,
             const float* __restrict__ convW, const float* __restrict__ convB,
             const float* __restrict__ Wdt, const float* __restrict__ bdt,
             const float* __restrict__ Alog, const float* __restrict__ Dpw, int i0,
             float* __restrict__ PP, float* __restrict__ FF,
             const float* __restrict__ HH)
{
  const int TC2 = LL / NC2;
  const size_t SC2 = (size_t)BZ*NC2*DD*NN;
  const int inst = blockIdx.x / (BZ*NC2);
  const int rb = blockIdx.x - inst*(BZ*NC2);
  const int c = rb & (NC2-1);
  const int b = rb / NC2;
  const int ch = threadIdx.x;
  const int pi = inst >> 1, d = inst & 1;
  const int id = (i0+pi)*2 + d;

  const ushort_t* xb = pi ? XBb : XBa;
  const ushort_t* zb = pi ? ZBb : ZBa;
  const ushort_t* meta = (inst==0)?M00:(inst==1)?M01:(inst==2)?M10:M11;
  ushort_t* yb = (inst==0)?Y0:(inst==1)?Y1:(inst==2)?Y2:Y3;

  float cw[4];
  #pragma unroll
  for (int k=0;k<4;++k) cw[k] = convW[((size_t)id*DD+ch)*4 + k];
  const float cb = convB[id*DD + ch];
  float wd[4];
  #pragma unroll
  for (int r=0;r<4;++r) wd[r] = Wdt[((size_t)id*4 + r)*DD + ch];
  const float bd = bdt[id*DD + ch];
  float An[NN];
  #pragma unroll
  for (int n=0;n<NN;++n) An[n] = -__expf(Alog[((size_t)id*DD+ch)*NN + n]);
  const float dp = PASSC ? Dpw[id*DD + ch] : 0.f;

  bool fastA = true;
  #pragma unroll
  for (int n=0;n<NN;++n) fastA = fastA && (fabsf(An[n] + (float)(n+1)) < 1e-3f);

  const size_t sbase = (size_t)inst*SC2 + ((size_t)(b*NC2+c)*DD + ch)*NN;
  float h[NN], P[NN];
  float Sdt = 0.f;
  if (PASSC){
    #pragma unroll
    for (int n=0;n<NN;++n) h[n] = HH[sbase+n];
  } else {
    #pragma unroll
    for (int n=0;n<NN;++n){ h[n]=0.f; P[n]=1.f; }
  }

  const int stp = d ? -1 : 1;
  const int t0  = d ? (LL-1 - c*TC2) : (c*TC2);

  float p1=0.f, p2=0.f, p3=0.f;
  {
    int tp = t0 - stp;
    if ((unsigned)tp < LL) p1 = b2f(xb[((size_t)b*LL+tp)*DD+ch]);
    tp -= stp;
    if ((unsigned)tp < LL) p2 = b2f(xb[((size_t)b*LL+tp)*DD+ch]);
    tp -= stp;
    if ((unsigned)tp < LL) p3 = b2f(xb[((size_t)b*LL+tp)*DD+ch]);
  }

  int t = t0;
  for (int s=0; s<TC2; ++s, t+=stp){
    const size_t row = (size_t)b*LL + t;
    const float xv = b2f(xb[row*DD+ch]);
    const float xc = silu_(cb + cw[0]*p3 + cw[1]*p2 + cw[2]*p1 + cw[3]*xv);
    p3=p2; p2=p1; p1=xv;

    float mtv[20];
    {
      const uint2* mp = (const uint2*)(meta + row*20);
      #pragma unroll
      for (int q=0;q<5;++q){
        const uint2 w = mp[q];
        mtv[q*4+0] = b2f((ushort_t)(w.x & 0xFFFFu));
        mtv[q*4+1] = b2f((ushort_t)(w.x >> 16));
        mtv[q*4+2] = b2f((ushort_t)(w.y & 0xFFFFu));
        mtv[q*4+3] = b2f((ushort_t)(w.y >> 16));
      }
    }
    const float dpre = bd + mtv[0]*wd[0] + mtv[1]*wd[1] + mtv[2]*wd[2] + mtv[3]*wd[3];
    const float dt = softplus_(dpre);
    const float u = dt*xc;

    float dA[NN];
    if (fastA){
      const float E = __expf(-dt);
      const float E2 = E*E, E4 = E2*E2;
      dA[0]=E;    dA[1]=E2;    dA[2]=E2*E;  dA[3]=E4;
      dA[4]=E4*E; dA[5]=E4*E2; dA[6]=E4*E2*E; dA[7]=E4*E4;
      Sdt += dt;
    } else {
      #pragma unroll
      for (int n=0;n<NN;++n) dA[n] = __expf(dt*An[n]);
    }

    if (!PASSC){
      #pragma unroll
      for (int n=0;n<NN;++n) h[n] = fmaf(h[n], dA[n], u*mtv[4+n]);
      if (!fastA){
        #pragma unroll
        for (int n=0;n<NN;++n) P[n] *= dA[n];
      }
    } else {
      float y = 0.f;
      #pragma unroll
      for (int n=0;n<NN;++n){
        h[n] = fmaf(h[n], dA[n], u*mtv[4+n]);
        y = fmaf(h[n], mtv[12+n], y);
      }
      const float zv = b2f(zb[row*DD+ch]);
      yb[row*DD + ch] = f2b((y + xc*dp)*silu_(zv));
    }
  }

  if (!PASSC){
    if (fastA){
      const float E = __expf(-Sdt);
      const float E2 = E*E, E4 = E2*E2;
      P[0]=E;    P[1]=E2;    P[2]=E2*E;  P[3]=E4;
      P[4]=E4*E; P[5]=E4*E2; P[6]=E4*E2*E; P[7]=E4*E4;
    }
    #pragma unroll
    for (int n=0;n<NN;++n){ PP[sbase+n] = P[n]; FF[sbase+n] = h[n]; }
  }
}

// ---- fused 4-instance inter-chunk propagation ----
template<int NC2>
__global__ __launch_bounds__(256)
void k_mid4(const float* __restrict__ PP, const float* __restrict__ FF,
            float* __restrict__ HH)
{
  const size_t SC2 = (size_t)BZ*NC2*DD*NN;
  const int inst = blockIdx.x >> 3;
  const int idx = (blockIdx.x & 7)*256 + threadIdx.x;
  const int b  = idx >> 9;
  const int cn = idx & 511;
  const size_t base = (size_t)inst*SC2;
  float h = 0.f;
  #pragma unroll 4
  for (int c=0; c<NC2; ++c){
    const size_t a2 = base + (((size_t)(b*NC2+c))<<9) + cn;
    HH[a2] = h;
    h = h*PP[a2] + FF[a2];
  }
}

// ---- unpack a 64-elem bf16 row (sum of two) ----
__device__ __forceinline__ void load_y2(const ushort_t* Ya, const ushort_t* Yb,
                                        size_t row, float* y)
{
  const uint4* pa = (const uint4*)(Ya + row);
  const uint4* pb = (const uint4*)(Yb + row);
  #pragma unroll
  for (int q=0;q<8;++q){
    uint4 va = pa[q], vb = pb[q];
    const uint_t aw[4] = {va.x, va.y, va.z, va.w};
    const uint_t bw[4] = {vb.x, vb.y, vb.z, vb.w};
    #pragma unroll
    for (int r=0;r<4;++r){
      y[q*8 + r*2 + 0] = b2f((ushort_t)(aw[r] & 0xFFFFu)) + b2f((ushort_t)(bw[r] & 0xFFFFu));
      y[q*8 + r*2 + 1] = b2f((ushort_t)(aw[r] >> 16))     + b2f((ushort_t)(bw[r] >> 16));
    }
  }
}

// ---- pair {0,1} output ----
__global__ __launch_bounds__(256)
void k_out2(const ushort_t* __restrict__ Y0, const ushort_t* __restrict__ Y1,
            const ushort_t* __restrict__ Y2, const ushort_t* __restrict__ Y3,
            const float* __restrict__ skipA, const float* __restrict__ skipB,
            const float* __restrict__ Wout, const float* __restrict__ bout,
            float* __restrict__ dstA, float* __restrict__ dstB)
{
  const int pi = blockIdx.x >> 8;
  const int pos = (blockIdx.x & 255)*256 + threadIdx.x;
  const int b = pos >> 14;
  const int l = pos & (LL-1);
  const size_t row = ((size_t)b*LL + l)*DD;

  const ushort_t* Ya = pi ? Y2 : Y0;
  const ushort_t* Yb = pi ? Y3 : Y1;
  const float* skip = pi ? skipB : skipA;
  float* dst = pi ? dstB : dstA;
  const float* Wo = Wout + (size_t)pi*DD*DD;
  const float* bo = bout + pi*DD;

  float y[DD];
  load_y2(Ya, Yb, row, y);
  for (int g=0; g<4; ++g){
    float acc[16];
    #pragma unroll
    for (int j=0;j<16;++j) acc[j]=0.f;
    #pragma unroll
    for (int k=0;k<DD;++k){
      const float av = y[k];
      const float* wr = Wo + k*DD + g*16;
      #pragma unroll
      for (int j=0;j<16;++j) acc[j] = fmaf(av, wr[j], acc[j]);
    }
    #pragma unroll
    for (int j=0;j<16;++j){
      const int col = g*16 + j;
      const size_t o = ((size_t)(b*DD+col))*LL + l;
      dst[o] = acc[j] + bo[col] + skip[o];
    }
  }
}

// ---- tail megakernel ----
__global__ __launch_bounds__(256)
void k_tail(const ushort_t* __restrict__ Y0, const ushort_t* __restrict__ Y1,
            const ushort_t* __restrict__ Y2, const ushort_t* __restrict__ Y3,
            const float* __restrict__ X1, const float* __restrict__ X2,
            const float* __restrict__ Wout, const float* __restrict__ bout,
            const float* __restrict__ Wfo, const float* __restrict__ bfo,
            float* __restrict__ ob)
{
  const int gid = blockIdx.x*256 + threadIdx.x;
  const int b = gid >> 14;
  const int l = gid & (LL-1);
  const size_t row = ((size_t)b*LL + l)*DD;

  float s[DD];
  float y[DD];
  {
    load_y2(Y0, Y1, row, y);
    const float* Wo = Wout + 2*DD*DD;
    const float* bo = bout + 2*DD;
    for (int g=0; g<4; ++g){
      float acc[16];
      #pragma unroll
      for (int j=0;j<16;++j) acc[j]=0.f;
      #pragma unroll
      for (int k=0;k<DD;++k){
        const float av = y[k];
        const float* wr = Wo + k*DD + g*16;
        #pragma unroll
        for (int j=0;j<16;++j) acc[j] = fmaf(av, wr[j], acc[j]);
      }
      #pragma unroll
      for (int j=0;j<16;++j){
        const int col = g*16 + j;
        s[col] = acc[j] + bo[col] + X1[((size_t)(b*DD+col))*LL + l];
      }
    }
  }
  {
    load_y2(Y2, Y3, row, y);
    const float* Wo = Wout + 3*DD*DD;
    const float* bo = bout + 3*DD;
    for (int g=0; g<4; ++g){
      float acc[16];
      #pragma unroll
      for (int j=0;j<16;++j) acc[j]=0.f;
      #pragma unroll
      for (int k=0;k<DD;++k){
        const float av = y[k];
        const float* wr = Wo + k*DD + g*16;
        #pragma unroll
        for (int j=0;j<16;++j) acc[j] = fmaf(av, wr[j], acc[j]);
      }
      #pragma unroll
      for (int j=0;j<16;++j){
        const int col = g*16 + j;
        s[col] += acc[j] + bo[col] + X2[((size_t)(b*DD+col))*LL + l];
      }
    }
  }
  for (int g=0; g<4; ++g){
    float acc[16];
    #pragma unroll
    for (int j=0;j<16;++j) acc[j]=0.f;
    #pragma unroll
    for (int k=0;k<DD;++k){
      const float av = s[k];
      const float* wr = Wfo + k*DD + g*16;
      #pragma unroll
      for (int j=0;j<16;++j) acc[j] = fmaf(av, wr[j], acc[j]);
    }
    #pragma unroll
    for (int j=0;j<16;++j){
      const int col = g*16 + j;
      const size_t o = ((size_t)(b*DD+col))*LL + l;
      const float fu = acc[j] + bfo[col];
      ob[o]       = X1[o] + fu;
      ob[BLD + o] = X2[o] + fu;
    }
  }
}

__global__ __launch_bounds__(256)
void k_copy4(const float* __restrict__ s, float* __restrict__ o)
{
  const size_t i = (size_t)blockIdx.x*256 + threadIdx.x;
  ((float4*)o)[i] = ((const float4*)s)[i];
}

// ================= fallback path (R14, f32 end-to-end) =================
__global__ __launch_bounds__(256)
void f_in(const float* __restrict__ src0, const float* __restrict__ src1,
          const float* __restrict__ lng0, const float* __restrict__ lnb0,
          const float* __restrict__ lng1, const float* __restrict__ lnb1,
          const float* __restrict__ W_in, const float* __restrict__ W_ine,
          const float* __restrict__ W_x, int i,
          float* __restrict__ XB, float* __restrict__ ZB,
          float* __restrict__ M0, float* __restrict__ M1)
{
  const int gid = blockIdx.x*256 + threadIdx.x;
  const int b = gid >> 14;
  const int l = gid & (LL-1);

  float a[DD];
  for (int ch=0; ch<DD; ++ch) a[ch] = src0[((size_t)(b*DD+ch))*LL + l];
  {
    float m=0.f; for (int k=0;k<DD;++k) m += a[k];  m *= (1.f/DD);
    float v=0.f; for (int k=0;k<DD;++k){ float d=a[k]-m; v += d*d; }  v *= (1.f/DD);
    float rs = rsqrtf(v + 1e-5f);
    for (int k=0;k<DD;++k) a[k] = (a[k]-m)*rs*lng0[i*DD+k] + lnb0[i*DD+k];
  }
  const float* Wi = W_in + (size_t)i*DD*2*DD;
  float* xrow = XB + ((size_t)b*LL + l)*DD;
  float* zrow = ZB + ((size_t)b*LL + l)*DD;
  for (int g=0; g<8; ++g){
    float acc[16];
    #pragma unroll
    for (int j=0;j<16;++j) acc[j]=0.f;
    for (int k=0;k<DD;++k){
      const float av = a[k];
      const float* wr = Wi + k*128 + g*16;
      #pragma unroll
      for (int j=0;j<16;++j) acc[j] = fmaf(av, wr[j], acc[j]);
    }
    float* drow = (g<4) ? (xrow + g*16) : (zrow + (g-4)*16);
    #pragma unroll
    for (int q=0;q<4;++q)
      ((float4*)drow)[q] = make_float4(acc[4*q],acc[4*q+1],acc[4*q+2],acc[4*q+3]);
  }
  float e[DD], ee[DD];
  for (int ch=0; ch<DD; ++ch) e[ch] = src1[((size_t)(b*DD+ch))*LL + l];
  {
    float m=0.f; for (int k=0;k<DD;++k) m += e[k];  m *= (1.f/DD);
    float v=0.f; for (int k=0;k<DD;++k){ float d=e[k]-m; v += d*d; }  v *= (1.f/DD);
    float rs = rsqrtf(v + 1e-5f);
    for (int k=0;k<DD;++k) e[k] = (e[k]-m)*rs*lng1[i*DD+k] + lnb1[i*DD+k];
  }
  const float* We = W_ine + (size_t)i*DD*DD;
  for (int m2=0; m2<DD; ++m2){
    float s = 0.f;
    for (int k=0;k<DD;++k) s = fmaf(e[k], We[k*DD + m2], s);
    ee[m2] = s;
  }
  for (int d=0; d<2; ++d){
    float acc[20];
    #pragma unroll
    for (int j=0;j<20;++j) acc[j]=0.f;
    for (int m2=0; m2<DD; ++m2){
      const float ev = ee[m2];
      const float* wr = W_x + ((size_t)(i*2+d)*DD + m2)*20;
      #pragma unroll
      for (int j=0;j<20;++j) acc[j] = fmaf(ev, wr[j], acc[j]);
    }
    float* mrow = (d ? M1 : M0) + ((size_t)b*LL + l)*20;
    #pragma unroll
    for (int q=0;q<5;++q)
      ((float4*)mrow)[q] = make_float4(acc[4*q],acc[4*q+1],acc[4*q+2],acc[4*q+3]);
  }
}

template<int DIR, bool PASSC>
__global__ __launch_bounds__(64)
void f_scan(const float* __restrict__ xb, const float* __restrict__ zb,
            float* __restrict__ yb, const float* __restrict__ meta,
            const float* __restrict__ convW, const float* __restrict__ convB,
            const float* __restrict__ Wdt, const float* __restrict__ bdt,
            const float* __restrict__ Alog, const float* __restrict__ Dpw, int id,
            float* __restrict__ Pb, float* __restrict__ Fb,
            const float* __restrict__ Hin)
{
  const int ch = threadIdx.x;
  const int c  = blockIdx.x & 255;
  const int b  = blockIdx.x >> 8;

  float cw[4];
  for (int k=0;k<4;++k) cw[k] = convW[((size_t)id*DD+ch)*4 + k];
  const float cb = convB[id*DD + ch];
  float wd[4]; for (int r=0;r<4;++r) wd[r] = Wdt[((size_t)id*4 + r)*DD + ch];
  const float bd = bdt[id*DD + ch];
  float An[NN]; for (int n=0;n<NN;++n) An[n] = -__expf(Alog[((size_t)id*DD+ch)*NN + n]);
  const float dp = PASSC ? Dpw[id*DD + ch] : 0.f;

  const size_t sbase = ((size_t)(b*256+c)*DD + ch)*NN;
  float h[NN], P[NN];
  if (PASSC){
    #pragma unroll
    for (int n=0;n<NN;++n) h[n] = Hin[sbase+n];
  } else {
    #pragma unroll
    for (int n=0;n<NN;++n){ h[n]=0.f; P[n]=1.f; }
  }

  int t0, stp;
  if (DIR==0){ t0 = c*64;        stp =  1; }
  else       { t0 = LL-1 - c*64; stp = -1; }

  float p1=0.f, p2=0.f, p3=0.f;
  {
    int tp = t0 - stp;
    if ((unsigned)tp < LL) p1 = xb[((size_t)b*LL+tp)*DD+ch];
    tp -= stp;
    if ((unsigned)tp < LL) p2 = xb[((size_t)b*LL+tp)*DD+ch];
    tp -= stp;
    if ((unsigned)tp < LL) p3 = xb[((size_t)b*LL+tp)*DD+ch];
  }

  int t = t0;
  for (int s=0; s<64; ++s, t+=stp){
    const size_t row = (size_t)b*LL + t;
    const float xv = xb[row*DD+ch];
    const float xc = silu_(cb + cw[0]*p3 + cw[1]*p2 + cw[2]*p1 + cw[3]*xv);
    p3=p2; p2=p1; p1=xv;

    const float* mt = meta + row*20;
    const float dpre = bd + mt[0]*wd[0] + mt[1]*wd[1] + mt[2]*wd[2] + mt[3]*wd[3];
    const float dt = softplus_(dpre);
    const float u = dt*xc;

    if (!PASSC){
      #pragma unroll
      for (int n=0;n<NN;++n){
        const float dA = __expf(dt*An[n]);
        h[n] = h[n]*dA + u*mt[4+n];
        P[n] *= dA;
      }
    } else {
      float y = 0.f;
      #pragma unroll
      for (int n=0;n<NN;++n){
        const float dA = __expf(dt*An[n]);
        h[n] = h[n]*dA + u*mt[4+n];
        y = fmaf(h[n], mt[12+n], y);
      }
      const float zv = zb[row*DD+ch];
      const float o = (y + xc*dp)*silu_(zv);
      float* yp = yb + row*DD + ch;
      if (DIR==0) *yp = o; else *yp += o;
    }
  }

  if (!PASSC){
    #pragma unroll
    for (int n=0;n<NN;++n){ Pb[sbase+n] = P[n]; Fb[sbase+n] = h[n]; }
  }
}

__global__ __launch_bounds__(256)
void f_mid(const float* __restrict__ Pb, const float* __restrict__ Fb,
           float* __restrict__ Hin)
{
  const int idx = blockIdx.x*256 + threadIdx.x;
  const int b  = idx >> 9;
  const int cn = idx & 511;
  float h = 0.f;
  #pragma unroll 4
  for (int c=0; c<256; ++c){
    const size_t a2 = (((size_t)(b*256+c))<<9) + cn;
    Hin[a2] = h;
    h = h*Pb[a2] + Fb[a2];
  }
}

template<int MODE>
__global__ __launch_bounds__(256)
void f_out(const float* __restrict__ YB, const float* __restrict__ skip,
           const float* __restrict__ Wo, const float* __restrict__ bo,
           float* __restrict__ dst)
{
  const int gid = blockIdx.x*256 + threadIdx.x;
  const int b = gid >> 14;
  const int l = gid & (LL-1);
  float y[DD];
  {
    const float4* s4 = (const float4*)(YB + ((size_t)b*LL + l)*DD);
    #pragma unroll
    for (int q=0;q<16;++q){ float4 v=s4[q]; y[4*q]=v.x; y[4*q+1]=v.y; y[4*q+2]=v.z; y[4*q+3]=v.w; }
  }
  for (int g=0; g<4; ++g){
    float acc[16];
    #pragma unroll
    for (int j=0;j<16;++j) acc[j]=0.f;
    for (int k=0;k<DD;++k){
      const float av = y[k];
      const float* wr = Wo + k*DD + g*16;
      #pragma unroll
      for (int j=0;j<16;++j) acc[j] = fmaf(av, wr[j], acc[j]);
    }
    #pragma unroll
    for (int j=0;j<16;++j){
      const int col = g*16 + j;
      const size_t o = ((size_t)(b*DD+col))*LL + l;
      float s = acc[j] + bo[col] + skip[o];
      if (MODE==1) s += dst[o];
      dst[o] = s;
    }
  }
}

__global__ __launch_bounds__(256)
void f_fuse(const float* __restrict__ FS, const float* __restrict__ X1,
            const float* __restrict__ X2, const float* __restrict__ Wfo,
            const float* __restrict__ bfo, float* __restrict__ ob)
{
  const int gid = blockIdx.x*256 + threadIdx.x;
  const int b = gid >> 14;
  const int l = gid & (LL-1);
  float fs[DD];
  for (int ch=0; ch<DD; ++ch) fs[ch] = FS[((size_t)(b*DD+ch))*LL + l];
  for (int g=0; g<4; ++g){
    float acc[16];
    #pragma unroll
    for (int j=0;j<16;++j) acc[j]=0.f;
    for (int k=0;k<DD;++k){
      const float av = fs[k];
      const float* wr = Wfo + k*DD + g*16;
      #pragma unroll
      for (int j=0;j<16;++j) acc[j] = fmaf(av, wr[j], acc[j]);
    }
    #pragma unroll
    for (int j=0;j<16;++j){
      const int col = g*16 + j;
      const size_t o = ((size_t)(b*DD+col))*LL + l;
      const float fu = acc[j] + bfo[col];
      ob[o]       = X1[o] + fu;
      ob[BLD + o] = X2[o] + fu;
    }
  }
}

extern "C" void kernel_launch(void* const* d_in, const int* in_sizes, int n_in,
                              void* d_out, int out_size, void* d_ws, size_t ws_size,
                              hipStream_t stream)
{
  static const int dictsz[21]  = {4194304,4194304,4194304,4194304,256,256,256,256,
                                  32768,16384,2048,512,10240,2048,512,4096,512,
                                  16384,256,4096,64};
  int map[21];
  bool okd = (n_in >= 21);
  if (okd) for (int i=0;i<21;++i) if (in_sizes[i] != dictsz[i]) { okd = false; break; }
  if (okd){
    for (int i=0;i<21;++i) map[i] = i;
  } else {
    bool used[64];
    for (int j=0;j<64;++j) used[j]=false;
    for (int i=0;i<21;++i){
      map[i] = -1;
      for (int j=0;j<n_in && j<64;++j)
        if (!used[j] && in_sizes[j]==dictsz[i]){ map[i]=j; used[j]=true; break; }
      if (map[i] < 0) map[i] = (i < n_in ? i : 0);
    }
  }

  const float* img1 = (const float*)d_in[map[0]];
  const float* img2 = (const float*)d_in[map[1]];
  const float* s1   = (const float*)d_in[map[2]];
  const float* s2   = (const float*)d_in[map[3]];
  const float* lng0 = (const float*)d_in[map[4]];
  const float* lnb0 = (const float*)d_in[map[5]];
  const float* lng1 = (const float*)d_in[map[6]];
  const float* lnb1 = (const float*)d_in[map[7]];
  const float* Win  = (const float*)d_in[map[8]];
  const float* Wine = (const float*)d_in[map[9]];
  const float* convW= (const float*)d_in[map[10]];
  const float* convB= (const float*)d_in[map[11]];
  const float* Wx   = (const float*)d_in[map[12]];
  const float* Wdt  = (const float*)d_in[map[13]];
  const float* bdt  = (const float*)d_in[map[14]];
  const float* Alog = (const float*)d_in[map[15]];
  const float* Dp   = (const float*)d_in[map[16]];
  const float* Wout = (const float*)d_in[map[17]];
  const float* bout = (const float*)d_in[map[18]];
  const float* Wfo  = (const float*)d_in[map[19]];
  const float* bfo  = (const float*)d_in[map[20]];

  float* ob = (float*)d_out;
  float* ws = (float*)d_ws;

  // pass-through outputs 2/3
  k_copy4<<<4096,256,0,stream>>>(s1, ob + 2*BLD);
  k_copy4<<<4096,256,0,stream>>>(s2, ob + 3*BLD);

  const size_t SCN512 = (size_t)BZ*512*DD*NN;   // 1,048,576
  const size_t SCN256 = (size_t)BZ*256*DD*NN;   // 524,288
  const size_t need512 = (10*BLD + 4*BML + 12*SCN512 + 64)*sizeof(float);
  const size_t need256 = (10*BLD + 4*BML + 12*SCN256 + 64)*sizeof(float);

  if (ws_size >= need256){
    const bool big = (ws_size >= need512);
    const size_t SC = big ? SCN512 : SCN256;
    float* X1  = ws;
    float* X2  = ws + 1*BLD;
    ushort_t* XBa = (ushort_t*)(ws + 2*BLD);
    ushort_t* ZBa = (ushort_t*)(ws + 3*BLD);
    ushort_t* XBb = (ushort_t*)(ws + 4*BLD);
    ushort_t* ZBb = (ushort_t*)(ws + 5*BLD);
    ushort_t* Y0  = (ushort_t*)(ws + 6*BLD);
    ushort_t* Y1  = (ushort_t*)(ws + 7*BLD);
    ushort_t* Y2  = (ushort_t*)(ws + 8*BLD);
    ushort_t* Y3  = (ushort_t*)(ws + 9*BLD);
    ushort_t* M00 = (ushort_t*)(ws + 10*BLD);
    ushort_t* M01 = (ushort_t*)(ws + 10*BLD + BML);
    ushort_t* M10 = (ushort_t*)(ws + 10*BLD + 2*BML);
    ushort_t* M11 = (ushort_t*)(ws + 10*BLD + 3*BML);
    float* PP  = ws + 10*BLD + 4*BML;
    float* FF  = PP + 4*SC;
    float* HH  = FF + 4*SC;

    for (int pr=0; pr<2; ++pr){
      const int i0 = pr*2;
      if (pr==0)
        k_in2<<<1024,256,0,stream>>>(img1, s1, img2, s2, lng0,lnb0,lng1,lnb1,
                                     Win, Wine, Wx, 0, XBa,ZBa,XBb,ZBb, M00,M01,M10,M11);
      else
        k_in2<<<1024,256,0,stream>>>(X1, X2, X2, X1, lng0,lnb0,lng1,lnb1,
                                     Win, Wine, Wx, 2, XBa,ZBa,XBb,ZBb, M00,M01,M10,M11);
      if (big){
        k_scan4<512,false><<<4*BZ*512,64,0,stream>>>(XBa,XBb,ZBa,ZBb, Y0,Y1,Y2,Y3,
                                                     M00,M01,M10,M11, convW,convB,Wdt,bdt,Alog,Dp,
                                                     i0, PP,FF,HH);
        k_mid4<512><<<32,256,0,stream>>>(PP,FF,HH);
        k_scan4<512,true ><<<4*BZ*512,64,0,stream>>>(XBa,XBb,ZBa,ZBb, Y0,Y1,Y2,Y3,
                                                     M00,M01,M10,M11, convW,convB,Wdt,bdt,Alog,Dp,
                                                     i0, PP,FF,HH);
      } else {
        k_scan4<256,false><<<4*BZ*256,64,0,stream>>>(XBa,XBb,ZBa,ZBb, Y0,Y1,Y2,Y3,
                                                     M00,M01,M10,M11, convW,convB,Wdt,bdt,Alog,Dp,
                                                     i0, PP,FF,HH);
        k_mid4<256><<<32,256,0,stream>>>(PP,FF,HH);
        k_scan4<256,true ><<<4*BZ*256,64,0,stream>>>(XBa,XBb,ZBa,ZBb, Y0,Y1,Y2,Y3,
                                                     M00,M01,M10,M11, convW,convB,Wdt,bdt,Alog,Dp,
                                                     i0, PP,FF,HH);
      }
      if (pr==0)
        k_out2<<<512,256,0,stream>>>(Y0,Y1,Y2,Y3, img1,img2, Wout,bout, X1,X2);
      else
        k_tail<<<256,256,0,stream>>>(Y0,Y1,Y2,Y3, X1,X2, Wout,bout, Wfo,bfo, ob);
    }
    return;
  }

  // ---- fallback (R14 structure, f32) ----
  float* X1 = ws;
  float* X2 = ws + 1*BLD;
  float* FS = ws + 2*BLD;
  float* XB = ws + 3*BLD;
  float* ZB = ws + 4*BLD;
  float* YB = ws + 5*BLD;
  float* M0 = ws + 6*BLD;
  float* M1 = M0 + BML;
  float* PP = M1 + BML;
  float* FF = PP + SCN256;
  float* HH = FF + SCN256;

  const size_t need = (6*BLD + 2*BML + 3*SCN256 + 64)*sizeof(float);
  if (ws_size < need) return;

  const float* bx0[4] = {img1, img2, X1, X2};
  const float* bx1[4] = {s1,   s2,   X2, X1};

  for (int i=0; i<4; ++i){
    f_in<<<256,256,0,stream>>>(bx0[i], bx1[i], lng0, lnb0, lng1, lnb1,
                               Win, Wine, Wx, i, XB, ZB, M0, M1);
    for (int d=0; d<2; ++d){
      const int id = i*2+d;
      const float* Md = d ? M1 : M0;
      if (d==0){
        f_scan<0,false><<<BZ*256,64,0,stream>>>(XB,nullptr,nullptr,Md,convW,convB,Wdt,bdt,Alog,nullptr,id,PP,FF,nullptr);
        f_mid<<<8,256,0,stream>>>(PP,FF,HH);
        f_scan<0,true ><<<BZ*256,64,0,stream>>>(XB,ZB,YB,Md,convW,convB,Wdt,bdt,Alog,Dp,id,nullptr,nullptr,HH);
      } else {
        f_scan<1,false><<<BZ*256,64,0,stream>>>(XB,nullptr,nullptr,Md,convW,convB,Wdt,bdt,Alog,nullptr,id,PP,FF,nullptr);
        f_mid<<<8,256,0,stream>>>(PP,FF,HH);
        f_scan<1,true ><<<BZ*256,64,0,stream>>>(XB,ZB,YB,Md,convW,convB,Wdt,bdt,Alog,Dp,id,nullptr,nullptr,HH);
      }
    }
    const float* Wop = Wout + (size_t)i*DD*DD;
    const float* bop = bout + (size_t)i*DD;
    if      (i==0) f_out<0><<<256,256,0,stream>>>(YB, img1, Wop, bop, X1);
    else if (i==1) f_out<0><<<256,256,0,stream>>>(YB, img2, Wop, bop, X2);
    else if (i==2) f_out<0><<<256,256,0,stream>>>(YB, X1,   Wop, bop, FS);
    else           f_out<1><<<256,256,0,stream>>>(YB, X2,   Wop, bop, FS);
  }
  f_fuse<<<256,256,0,stream>>>(FS, X1, X2, Wfo, bfo, ob);
}

// Round 26
// 760.088 us; speedup vs baseline: 1.0428x; 1.0428x over previous
//
#include <hip/hip_runtime.h>
#include <hip/hip_bf16.h>

#define BZ 4
#define DD 64
#define LL 16384
#define NN 8
#define BLD ((size_t)BZ*DD*LL)      // 4,194,304
#define BML ((size_t)BZ*20*LL)      // 1,310,720

typedef unsigned short ushort_t;
typedef unsigned int uint_t;

__device__ __forceinline__ float silu_(float x){ return __fdividef(x, 1.f + __expf(-x)); }
__device__ __forceinline__ float softplus_(float x){ return (x > 20.f) ? x : __logf(1.f + __expf(x)); }
__device__ __forceinline__ ushort_t f2b(float x){
  uint_t u = __float_as_uint(x);
  u = (u + 0x7FFFu + ((u >> 16) & 1u)) >> 16;
  return (ushort_t)u;
}
__device__ __forceinline__ float b2f(ushort_t h){ return __uint_as_float(((uint_t)h) << 16); }
__device__ __forceinline__ uint_t pk(float a, float b){ return (uint_t)f2b(a) | ((uint_t)f2b(b) << 16); }

// ================= fused path =================

// ---- input stage: sel = (pair, path); XB/ZB stored bf16 ----
__global__ __launch_bounds__(256)
void k_in2(const float* __restrict__ s0a, const float* __restrict__ s1a,
           const float* __restrict__ s0b, const float* __restrict__ s1b,
           const float* __restrict__ lng0, const float* __restrict__ lnb0,
           const float* __restrict__ lng1, const float* __restrict__ lnb1,
           const float* __restrict__ W_in, const float* __restrict__ W_ine,
           const float* __restrict__ W_x, int i0,
           ushort_t* __restrict__ XBa, ushort_t* __restrict__ ZBa,
           ushort_t* __restrict__ XBb, ushort_t* __restrict__ ZBb,
           float* __restrict__ M00, float* __restrict__ M01,
           float* __restrict__ M10, float* __restrict__ M11)
{
  const int sel  = blockIdx.x >> 8;                // 0..3
  const int pi   = sel & 1;
  const int path = sel >> 1;
  const int pos = (blockIdx.x & 255)*256 + threadIdx.x;
  const int b = pos >> 14;
  const int l = pos & (LL-1);
  const int i = i0 + pi;

  if (path == 0){
    const float* src0 = pi ? s0b : s0a;
    float a[DD];
    #pragma unroll
    for (int ch=0; ch<DD; ++ch) a[ch] = src0[((size_t)(b*DD+ch))*LL + l];
    float m=0.f;
    #pragma unroll
    for (int k=0;k<DD;++k) m += a[k];
    m *= (1.f/DD);
    float v=0.f;
    #pragma unroll
    for (int k=0;k<DD;++k){ float d=a[k]-m; v += d*d; }
    v *= (1.f/DD);
    const float rs = rsqrtf(v + 1e-5f);
    #pragma unroll
    for (int k=0;k<DD;++k) a[k] = (a[k]-m)*rs*lng0[i*DD+k] + lnb0[i*DD+k];

    const float* Wi = W_in + (size_t)i*DD*2*DD;
    ushort_t* xrow = (pi ? XBb : XBa) + ((size_t)b*LL + l)*DD;
    ushort_t* zrow = (pi ? ZBb : ZBa) + ((size_t)b*LL + l)*DD;
    for (int g=0; g<8; ++g){
      float acc[16];
      #pragma unroll
      for (int j=0;j<16;++j) acc[j]=0.f;
      #pragma unroll
      for (int k=0;k<DD;++k){
        const float av = a[k];
        const float* wr = Wi + k*128 + g*16;
        #pragma unroll
        for (int j=0;j<16;++j) acc[j] = fmaf(av, wr[j], acc[j]);
      }
      ushort_t* drow = (g<4) ? (xrow + g*16) : (zrow + (g-4)*16);
      uint4 o0, o1;
      o0.x = pk(acc[0],acc[1]);  o0.y = pk(acc[2],acc[3]);
      o0.z = pk(acc[4],acc[5]);  o0.w = pk(acc[6],acc[7]);
      o1.x = pk(acc[8],acc[9]);  o1.y = pk(acc[10],acc[11]);
      o1.z = pk(acc[12],acc[13]);o1.w = pk(acc[14],acc[15]);
      ((uint4*)drow)[0] = o0;
      ((uint4*)drow)[1] = o1;
    }
  } else {
    const float* src1 = pi ? s1b : s1a;
    float e[DD];
    #pragma unroll
    for (int ch=0; ch<DD; ++ch) e[ch] = src1[((size_t)(b*DD+ch))*LL + l];
    float m=0.f;
    #pragma unroll
    for (int k=0;k<DD;++k) m += e[k];
    m *= (1.f/DD);
    float v=0.f;
    #pragma unroll
    for (int k=0;k<DD;++k){ float d=e[k]-m; v += d*d; }
    v *= (1.f/DD);
    const float rs = rsqrtf(v + 1e-5f);
    #pragma unroll
    for (int k=0;k<DD;++k) e[k] = (e[k]-m)*rs*lng1[i*DD+k] + lnb1[i*DD+k];

    const float* We  = W_ine + (size_t)i*DD*DD;
    const float* Wx0 = W_x + ((size_t)(i*2+0)*DD)*20;
    const float* Wx1 = W_x + ((size_t)(i*2+1)*DD)*20;
    float acc0[20], acc1[20];
    #pragma unroll
    for (int j=0;j<20;++j){ acc0[j]=0.f; acc1[j]=0.f; }
    for (int gg=0; gg<4; ++gg){
      float eeg[16];
      #pragma unroll
      for (int j=0;j<16;++j) eeg[j]=0.f;
      #pragma unroll
      for (int k=0;k<DD;++k){
        const float ev = e[k];
        const float* wr = We + k*DD + gg*16;
        #pragma unroll
        for (int j=0;j<16;++j) eeg[j] = fmaf(ev, wr[j], eeg[j]);
      }
      const float* w0 = Wx0 + (size_t)(gg*16)*20;
      const float* w1 = Wx1 + (size_t)(gg*16)*20;
      #pragma unroll
      for (int jj=0;jj<16;++jj){
        const float s = eeg[jj];
        #pragma unroll
        for (int j=0;j<20;++j){
          acc0[j] = fmaf(s, w0[jj*20+j], acc0[j]);
          acc1[j] = fmaf(s, w1[jj*20+j], acc1[j]);
        }
      }
    }
    float* mrow0 = (pi ? M10 : M00) + ((size_t)b*LL + l)*20;
    float* mrow1 = (pi ? M11 : M01) + ((size_t)b*LL + l)*20;
    #pragma unroll
    for (int q=0;q<5;++q){
      ((float4*)mrow0)[q] = make_float4(acc0[4*q],acc0[4*q+1],acc0[4*q+2],acc0[4*q+3]);
      ((float4*)mrow1)[q] = make_float4(acc1[4*q],acc1[4*q+1],acc1[4*q+2],acc1[4*q+3]);
    }
  }
}

// ---- fused 4-instance chunked scan; xb/zb/yb in bf16 ----
template<int NC2, bool PASSC>
__global__ __launch_bounds__(64)
void k_scan4(const ushort_t* __restrict__ XBa, const ushort_t* __restrict__ XBb,
             const ushort_t* __restrict__ ZBa, const ushort_t* __restrict__ ZBb,
             ushort_t* __restrict__ Y0, ushort_t* __restrict__ Y1,
             ushort_t* __restrict__ Y2, ushort_t* __restrict__ Y3,
             const float* __restrict__ M00, const float* __restrict__ M01,
             const float* __restrict__ M10, const float* __restrict__ M11,
             const float* __restrict__ convW, const float* __restrict__ convB,
             const float* __restrict__ Wdt, const float* __restrict__ bdt,
             const float* __restrict__ Alog, const float* __restrict__ Dpw, int i0,
             float* __restrict__ PP, float* __restrict__ FF,
             const float* __restrict__ HH)
{
  const int TC2 = LL / NC2;
  const size_t SC2 = (size_t)BZ*NC2*DD*NN;
  const int inst = blockIdx.x / (BZ*NC2);
  const int rb = blockIdx.x - inst*(BZ*NC2);
  const int c = rb & (NC2-1);
  const int b = rb / NC2;
  const int ch = threadIdx.x;
  const int pi = inst >> 1, d = inst & 1;
  const int id = (i0+pi)*2 + d;

  const ushort_t* xb = pi ? XBb : XBa;
  const ushort_t* zb = pi ? ZBb : ZBa;
  const float* meta = (inst==0)?M00:(inst==1)?M01:(inst==2)?M10:M11;
  ushort_t* yb = (inst==0)?Y0:(inst==1)?Y1:(inst==2)?Y2:Y3;

  float cw[4];
  #pragma unroll
  for (int k=0;k<4;++k) cw[k] = convW[((size_t)id*DD+ch)*4 + k];
  const float cb = convB[id*DD + ch];
  float wd[4];
  #pragma unroll
  for (int r=0;r<4;++r) wd[r] = Wdt[((size_t)id*4 + r)*DD + ch];
  const float bd = bdt[id*DD + ch];
  float An[NN];
  #pragma unroll
  for (int n=0;n<NN;++n) An[n] = -__expf(Alog[((size_t)id*DD+ch)*NN + n]);
  const float dp = PASSC ? Dpw[id*DD + ch] : 0.f;

  bool fastA = true;
  #pragma unroll
  for (int n=0;n<NN;++n) fastA = fastA && (fabsf(An[n] + (float)(n+1)) < 1e-3f);

  const size_t sbase = (size_t)inst*SC2 + ((size_t)(b*NC2+c)*DD + ch)*NN;
  float h[NN], P[NN];
  float Sdt = 0.f;
  if (PASSC){
    #pragma unroll
    for (int n=0;n<NN;++n) h[n] = HH[sbase+n];
  } else {
    #pragma unroll
    for (int n=0;n<NN;++n){ h[n]=0.f; P[n]=1.f; }
  }

  const int stp = d ? -1 : 1;
  const int t0  = d ? (LL-1 - c*TC2) : (c*TC2);

  float p1=0.f, p2=0.f, p3=0.f;
  {
    int tp = t0 - stp;
    if ((unsigned)tp < LL) p1 = b2f(xb[((size_t)b*LL+tp)*DD+ch]);
    tp -= stp;
    if ((unsigned)tp < LL) p2 = b2f(xb[((size_t)b*LL+tp)*DD+ch]);
    tp -= stp;
    if ((unsigned)tp < LL) p3 = b2f(xb[((size_t)b*LL+tp)*DD+ch]);
  }

  int t = t0;
  for (int s=0; s<TC2; ++s, t+=stp){
    const size_t row = (size_t)b*LL + t;
    const float xv = b2f(xb[row*DD+ch]);
    const float xc = silu_(cb + cw[0]*p3 + cw[1]*p2 + cw[2]*p1 + cw[3]*xv);
    p3=p2; p2=p1; p1=xv;

    const float* mt = meta + row*20;
    const float dpre = bd + mt[0]*wd[0] + mt[1]*wd[1] + mt[2]*wd[2] + mt[3]*wd[3];
    const float dt = softplus_(dpre);
    const float u = dt*xc;

    float dA[NN];
    if (fastA){
      const float E = __expf(-dt);
      const float E2 = E*E, E4 = E2*E2;
      dA[0]=E;    dA[1]=E2;    dA[2]=E2*E;  dA[3]=E4;
      dA[4]=E4*E; dA[5]=E4*E2; dA[6]=E4*E2*E; dA[7]=E4*E4;
      Sdt += dt;
    } else {
      #pragma unroll
      for (int n=0;n<NN;++n) dA[n] = __expf(dt*An[n]);
    }

    if (!PASSC){
      #pragma unroll
      for (int n=0;n<NN;++n) h[n] = fmaf(h[n], dA[n], u*mt[4+n]);
      if (!fastA){
        #pragma unroll
        for (int n=0;n<NN;++n) P[n] *= dA[n];
      }
    } else {
      float y = 0.f;
      #pragma unroll
      for (int n=0;n<NN;++n){
        h[n] = fmaf(h[n], dA[n], u*mt[4+n]);
        y = fmaf(h[n], mt[12+n], y);
      }
      const float zv = b2f(zb[row*DD+ch]);
      yb[row*DD + ch] = f2b((y + xc*dp)*silu_(zv));
    }
  }

  if (!PASSC){
    if (fastA){
      const float E = __expf(-Sdt);
      const float E2 = E*E, E4 = E2*E2;
      P[0]=E;    P[1]=E2;    P[2]=E2*E;  P[3]=E4;
      P[4]=E4*E; P[5]=E4*E2; P[6]=E4*E2*E; P[7]=E4*E4;
    }
    #pragma unroll
    for (int n=0;n<NN;++n){ PP[sbase+n] = P[n]; FF[sbase+n] = h[n]; }
  }
}

// ---- fused 4-instance inter-chunk propagation ----
template<int NC2>
__global__ __launch_bounds__(256)
void k_mid4(const float* __restrict__ PP, const float* __restrict__ FF,
            float* __restrict__ HH)
{
  const size_t SC2 = (size_t)BZ*NC2*DD*NN;
  const int inst = blockIdx.x >> 3;
  const int idx = (blockIdx.x & 7)*256 + threadIdx.x;
  const int b  = idx >> 9;
  const int cn = idx & 511;
  const size_t base = (size_t)inst*SC2;
  float h = 0.f;
  #pragma unroll 4
  for (int c=0; c<NC2; ++c){
    const size_t a2 = base + (((size_t)(b*NC2+c))<<9) + cn;
    HH[a2] = h;
    h = h*PP[a2] + FF[a2];
  }
}

// ---- unpack a 64-elem bf16 row (sum of two) ----
__device__ __forceinline__ void load_y2(const ushort_t* Ya, const ushort_t* Yb,
                                        size_t row, float* y)
{
  const uint4* pa = (const uint4*)(Ya + row);
  const uint4* pb = (const uint4*)(Yb + row);
  #pragma unroll
  for (int q=0;q<8;++q){
    uint4 va = pa[q], vb = pb[q];
    const uint_t aw[4] = {va.x, va.y, va.z, va.w};
    const uint_t bw[4] = {vb.x, vb.y, vb.z, vb.w};
    #pragma unroll
    for (int r=0;r<4;++r){
      y[q*8 + r*2 + 0] = b2f((ushort_t)(aw[r] & 0xFFFFu)) + b2f((ushort_t)(bw[r] & 0xFFFFu));
      y[q*8 + r*2 + 1] = b2f((ushort_t)(aw[r] >> 16))     + b2f((ushort_t)(bw[r] >> 16));
    }
  }
}

// ---- pair {0,1} output ----
__global__ __launch_bounds__(256)
void k_out2(const ushort_t* __restrict__ Y0, const ushort_t* __restrict__ Y1,
            const ushort_t* __restrict__ Y2, const ushort_t* __restrict__ Y3,
            const float* __restrict__ skipA, const float* __restrict__ skipB,
            const float* __restrict__ Wout, const float* __restrict__ bout,
            float* __restrict__ dstA, float* __restrict__ dstB)
{
  const int pi = blockIdx.x >> 8;
  const int pos = (blockIdx.x & 255)*256 + threadIdx.x;
  const int b = pos >> 14;
  const int l = pos & (LL-1);
  const size_t row = ((size_t)b*LL + l)*DD;

  const ushort_t* Ya = pi ? Y2 : Y0;
  const ushort_t* Yb = pi ? Y3 : Y1;
  const float* skip = pi ? skipB : skipA;
  float* dst = pi ? dstB : dstA;
  const float* Wo = Wout + (size_t)pi*DD*DD;
  const float* bo = bout + pi*DD;

  float y[DD];
  load_y2(Ya, Yb, row, y);
  for (int g=0; g<4; ++g){
    float acc[16];
    #pragma unroll
    for (int j=0;j<16;++j) acc[j]=0.f;
    #pragma unroll
    for (int k=0;k<DD;++k){
      const float av = y[k];
      const float* wr = Wo + k*DD + g*16;
      #pragma unroll
      for (int j=0;j<16;++j) acc[j] = fmaf(av, wr[j], acc[j]);
    }
    #pragma unroll
    for (int j=0;j<16;++j){
      const int col = g*16 + j;
      const size_t o = ((size_t)(b*DD+col))*LL + l;
      dst[o] = acc[j] + bo[col] + skip[o];
    }
  }
}

// ---- tail megakernel ----
__global__ __launch_bounds__(256)
void k_tail(const ushort_t* __restrict__ Y0, const ushort_t* __restrict__ Y1,
            const ushort_t* __restrict__ Y2, const ushort_t* __restrict__ Y3,
            const float* __restrict__ X1, const float* __restrict__ X2,
            const float* __restrict__ Wout, const float* __restrict__ bout,
            const float* __restrict__ Wfo, const float* __restrict__ bfo,
            float* __restrict__ ob)
{
  const int gid = blockIdx.x*256 + threadIdx.x;
  const int b = gid >> 14;
  const int l = gid & (LL-1);
  const size_t row = ((size_t)b*LL + l)*DD;

  float s[DD];
  float y[DD];
  {
    load_y2(Y0, Y1, row, y);
    const float* Wo = Wout + 2*DD*DD;
    const float* bo = bout + 2*DD;
    for (int g=0; g<4; ++g){
      float acc[16];
      #pragma unroll
      for (int j=0;j<16;++j) acc[j]=0.f;
      #pragma unroll
      for (int k=0;k<DD;++k){
        const float av = y[k];
        const float* wr = Wo + k*DD + g*16;
        #pragma unroll
        for (int j=0;j<16;++j) acc[j] = fmaf(av, wr[j], acc[j]);
      }
      #pragma unroll
      for (int j=0;j<16;++j){
        const int col = g*16 + j;
        s[col] = acc[j] + bo[col] + X1[((size_t)(b*DD+col))*LL + l];
      }
    }
  }
  {
    load_y2(Y2, Y3, row, y);
    const float* Wo = Wout + 3*DD*DD;
    const float* bo = bout + 3*DD;
    for (int g=0; g<4; ++g){
      float acc[16];
      #pragma unroll
      for (int j=0;j<16;++j) acc[j]=0.f;
      #pragma unroll
      for (int k=0;k<DD;++k){
        const float av = y[k];
        const float* wr = Wo + k*DD + g*16;
        #pragma unroll
        for (int j=0;j<16;++j) acc[j] = fmaf(av, wr[j], acc[j]);
      }
      #pragma unroll
      for (int j=0;j<16;++j){
        const int col = g*16 + j;
        s[col] += acc[j] + bo[col] + X2[((size_t)(b*DD+col))*LL + l];
      }
    }
  }
  for (int g=0; g<4; ++g){
    float acc[16];
    #pragma unroll
    for (int j=0;j<16;++j) acc[j]=0.f;
    #pragma unroll
    for (int k=0;k<DD;++k){
      const float av = s[k];
      const float* wr = Wfo + k*DD + g*16;
      #pragma unroll
      for (int j=0;j<16;++j) acc[j] = fmaf(av, wr[j], acc[j]);
    }
    #pragma unroll
    for (int j=0;j<16;++j){
      const int col = g*16 + j;
      const size_t o = ((size_t)(b*DD+col))*LL + l;
      const float fu = acc[j] + bfo[col];
      ob[o]       = X1[o] + fu;
      ob[BLD + o] = X2[o] + fu;
    }
  }
}

__global__ __launch_bounds__(256)
void k_copy4(const float* __restrict__ s, float* __restrict__ o)
{
  const size_t i = (size_t)blockIdx.x*256 + threadIdx.x;
  ((float4*)o)[i] = ((const float4*)s)[i];
}

// ================= fallback path (R14, f32 end-to-end) =================
__global__ __launch_bounds__(256)
void f_in(const float* __restrict__ src0, const float* __restrict__ src1,
          const float* __restrict__ lng0, const float* __restrict__ lnb0,
          const float* __restrict__ lng1, const float* __restrict__ lnb1,
          const float* __restrict__ W_in, const float* __restrict__ W_ine,
          const float* __restrict__ W_x, int i,
          float* __restrict__ XB, float* __restrict__ ZB,
          float* __restrict__ M0, float* __restrict__ M1)
{
  const int gid = blockIdx.x*256 + threadIdx.x;
  const int b = gid >> 14;
  const int l = gid & (LL-1);

  float a[DD];
  for (int ch=0; ch<DD; ++ch) a[ch] = src0[((size_t)(b*DD+ch))*LL + l];
  {
    float m=0.f; for (int k=0;k<DD;++k) m += a[k];  m *= (1.f/DD);
    float v=0.f; for (int k=0;k<DD;++k){ float d=a[k]-m; v += d*d; }  v *= (1.f/DD);
    float rs = rsqrtf(v + 1e-5f);
    for (int k=0;k<DD;++k) a[k] = (a[k]-m)*rs*lng0[i*DD+k] + lnb0[i*DD+k];
  }
  const float* Wi = W_in + (size_t)i*DD*2*DD;
  float* xrow = XB + ((size_t)b*LL + l)*DD;
  float* zrow = ZB + ((size_t)b*LL + l)*DD;
  for (int g=0; g<8; ++g){
    float acc[16];
    #pragma unroll
    for (int j=0;j<16;++j) acc[j]=0.f;
    for (int k=0;k<DD;++k){
      const float av = a[k];
      const float* wr = Wi + k*128 + g*16;
      #pragma unroll
      for (int j=0;j<16;++j) acc[j] = fmaf(av, wr[j], acc[j]);
    }
    float* drow = (g<4) ? (xrow + g*16) : (zrow + (g-4)*16);
    #pragma unroll
    for (int q=0;q<4;++q)
      ((float4*)drow)[q] = make_float4(acc[4*q],acc[4*q+1],acc[4*q+2],acc[4*q+3]);
  }
  float e[DD], ee[DD];
  for (int ch=0; ch<DD; ++ch) e[ch] = src1[((size_t)(b*DD+ch))*LL + l];
  {
    float m=0.f; for (int k=0;k<DD;++k) m += e[k];  m *= (1.f/DD);
    float v=0.f; for (int k=0;k<DD;++k){ float d=e[k]-m; v += d*d; }  v *= (1.f/DD);
    float rs = rsqrtf(v + 1e-5f);
    for (int k=0;k<DD;++k) e[k] = (e[k]-m)*rs*lng1[i*DD+k] + lnb1[i*DD+k];
  }
  const float* We = W_ine + (size_t)i*DD*DD;
  for (int m2=0; m2<DD; ++m2){
    float s = 0.f;
    for (int k=0;k<DD;++k) s = fmaf(e[k], We[k*DD + m2], s);
    ee[m2] = s;
  }
  for (int d=0; d<2; ++d){
    float acc[20];
    #pragma unroll
    for (int j=0;j<20;++j) acc[j]=0.f;
    for (int m2=0; m2<DD; ++m2){
      const float ev = ee[m2];
      const float* wr = W_x + ((size_t)(i*2+d)*DD + m2)*20;
      #pragma unroll
      for (int j=0;j<20;++j) acc[j] = fmaf(ev, wr[j], acc[j]);
    }
    float* mrow = (d ? M1 : M0) + ((size_t)b*LL + l)*20;
    #pragma unroll
    for (int q=0;q<5;++q)
      ((float4*)mrow)[q] = make_float4(acc[4*q],acc[4*q+1],acc[4*q+2],acc[4*q+3]);
  }
}

template<int DIR, bool PASSC>
__global__ __launch_bounds__(64)
void f_scan(const float* __restrict__ xb, const float* __restrict__ zb,
            float* __restrict__ yb, const float* __restrict__ meta,
            const float* __restrict__ convW, const float* __restrict__ convB,
            const float* __restrict__ Wdt, const float* __restrict__ bdt,
            const float* __restrict__ Alog, const float* __restrict__ Dpw, int id,
            float* __restrict__ Pb, float* __restrict__ Fb,
            const float* __restrict__ Hin)
{
  const int ch = threadIdx.x;
  const int c  = blockIdx.x & 255;
  const int b  = blockIdx.x >> 8;

  float cw[4];
  for (int k=0;k<4;++k) cw[k] = convW[((size_t)id*DD+ch)*4 + k];
  const float cb = convB[id*DD + ch];
  float wd[4]; for (int r=0;r<4;++r) wd[r] = Wdt[((size_t)id*4 + r)*DD + ch];
  const float bd = bdt[id*DD + ch];
  float An[NN]; for (int n=0;n<NN;++n) An[n] = -__expf(Alog[((size_t)id*DD+ch)*NN + n]);
  const float dp = PASSC ? Dpw[id*DD + ch] : 0.f;

  const size_t sbase = ((size_t)(b*256+c)*DD + ch)*NN;
  float h[NN], P[NN];
  if (PASSC){
    #pragma unroll
    for (int n=0;n<NN;++n) h[n] = Hin[sbase+n];
  } else {
    #pragma unroll
    for (int n=0;n<NN;++n){ h[n]=0.f; P[n]=1.f; }
  }

  int t0, stp;
  if (DIR==0){ t0 = c*64;        stp =  1; }
  else       { t0 = LL-1 - c*64; stp = -1; }

  float p1=0.f, p2=0.f, p3=0.f;
  {
    int tp = t0 - stp;
    if ((unsigned)tp < LL) p1 = xb[((size_t)b*LL+tp)*DD+ch];
    tp -= stp;
    if ((unsigned)tp < LL) p2 = xb[((size_t)b*LL+tp)*DD+ch];
    tp -= stp;
    if ((unsigned)tp < LL) p3 = xb[((size_t)b*LL+tp)*DD+ch];
  }

  int t = t0;
  for (int s=0; s<64; ++s, t+=stp){
    const size_t row = (size_t)b*LL + t;
    const float xv = xb[row*DD+ch];
    const float xc = silu_(cb + cw[0]*p3 + cw[1]*p2 + cw[2]*p1 + cw[3]*xv);
    p3=p2; p2=p1; p1=xv;

    const float* mt = meta + row*20;
    const float dpre = bd + mt[0]*wd[0] + mt[1]*wd[1] + mt[2]*wd[2] + mt[3]*wd[3];
    const float dt = softplus_(dpre);
    const float u = dt*xc;

    if (!PASSC){
      #pragma unroll
      for (int n=0;n<NN;++n){
        const float dA = __expf(dt*An[n]);
        h[n] = h[n]*dA + u*mt[4+n];
        P[n] *= dA;
      }
    } else {
      float y = 0.f;
      #pragma unroll
      for (int n=0;n<NN;++n){
        const float dA = __expf(dt*An[n]);
        h[n] = h[n]*dA + u*mt[4+n];
        y = fmaf(h[n], mt[12+n], y);
      }
      const float zv = zb[row*DD+ch];
      const float o = (y + xc*dp)*silu_(zv);
      float* yp = yb + row*DD + ch;
      if (DIR==0) *yp = o; else *yp += o;
    }
  }

  if (!PASSC){
    #pragma unroll
    for (int n=0;n<NN;++n){ Pb[sbase+n] = P[n]; Fb[sbase+n] = h[n]; }
  }
}

__global__ __launch_bounds__(256)
void f_mid(const float* __restrict__ Pb, const float* __restrict__ Fb,
           float* __restrict__ Hin)
{
  const int idx = blockIdx.x*256 + threadIdx.x;
  const int b  = idx >> 9;
  const int cn = idx & 511;
  float h = 0.f;
  #pragma unroll 4
  for (int c=0; c<256; ++c){
    const size_t a2 = (((size_t)(b*256+c))<<9) + cn;
    Hin[a2] = h;
    h = h*Pb[a2] + Fb[a2];
  }
}

template<int MODE>
__global__ __launch_bounds__(256)
void f_out(const float* __restrict__ YB, const float* __restrict__ skip,
           const float* __restrict__ Wo, const float* __restrict__ bo,
           float* __restrict__ dst)
{
  const int gid = blockIdx.x*256 + threadIdx.x;
  const int b = gid >> 14;
  const int l = gid & (LL-1);
  float y[DD];
  {
    const float4* s4 = (const float4*)(YB + ((size_t)b*LL + l)*DD);
    #pragma unroll
    for (int q=0;q<16;++q){ float4 v=s4[q]; y[4*q]=v.x; y[4*q+1]=v.y; y[4*q+2]=v.z; y[4*q+3]=v.w; }
  }
  for (int g=0; g<4; ++g){
    float acc[16];
    #pragma unroll
    for (int j=0;j<16;++j) acc[j]=0.f;
    for (int k=0;k<DD;++k){
      const float av = y[k];
      const float* wr = Wo + k*DD + g*16;
      #pragma unroll
      for (int j=0;j<16;++j) acc[j] = fmaf(av, wr[j], acc[j]);
    }
    #pragma unroll
    for (int j=0;j<16;++j){
      const int col = g*16 + j;
      const size_t o = ((size_t)(b*DD+col))*LL + l;
      float s = acc[j] + bo[col] + skip[o];
      if (MODE==1) s += dst[o];
      dst[o] = s;
    }
  }
}

__global__ __launch_bounds__(256)
void f_fuse(const float* __restrict__ FS, const float* __restrict__ X1,
            const float* __restrict__ X2, const float* __restrict__ Wfo,
            const float* __restrict__ bfo, float* __restrict__ ob)
{
  const int gid = blockIdx.x*256 + threadIdx.x;
  const int b = gid >> 14;
  const int l = gid & (LL-1);
  float fs[DD];
  for (int ch=0; ch<DD; ++ch) fs[ch] = FS[((size_t)(b*DD+ch))*LL + l];
  for (int g=0; g<4; ++g){
    float acc[16];
    #pragma unroll
    for (int j=0;j<16;++j) acc[j]=0.f;
    for (int k=0;k<DD;++k){
      const float av = fs[k];
      const float* wr = Wfo + k*DD + g*16;
      #pragma unroll
      for (int j=0;j<16;++j) acc[j] = fmaf(av, wr[j], acc[j]);
    }
    #pragma unroll
    for (int j=0;j<16;++j){
      const int col = g*16 + j;
      const size_t o = ((size_t)(b*DD+col))*LL + l;
      const float fu = acc[j] + bfo[col];
      ob[o]       = X1[o] + fu;
      ob[BLD + o] = X2[o] + fu;
    }
  }
}

extern "C" void kernel_launch(void* const* d_in, const int* in_sizes, int n_in,
                              void* d_out, int out_size, void* d_ws, size_t ws_size,
                              hipStream_t stream)
{
  static const int dictsz[21]  = {4194304,4194304,4194304,4194304,256,256,256,256,
                                  32768,16384,2048,512,10240,2048,512,4096,512,
                                  16384,256,4096,64};
  int map[21];
  bool okd = (n_in >= 21);
  if (okd) for (int i=0;i<21;++i) if (in_sizes[i] != dictsz[i]) { okd = false; break; }
  if (okd){
    for (int i=0;i<21;++i) map[i] = i;
  } else {
    bool used[64];
    for (int j=0;j<64;++j) used[j]=false;
    for (int i=0;i<21;++i){
      map[i] = -1;
      for (int j=0;j<n_in && j<64;++j)
        if (!used[j] && in_sizes[j]==dictsz[i]){ map[i]=j; used[j]=true; break; }
      if (map[i] < 0) map[i] = (i < n_in ? i : 0);
    }
  }

  const float* img1 = (const float*)d_in[map[0]];
  const float* img2 = (const float*)d_in[map[1]];
  const float* s1   = (const float*)d_in[map[2]];
  const float* s2   = (const float*)d_in[map[3]];
  const float* lng0 = (const float*)d_in[map[4]];
  const float* lnb0 = (const float*)d_in[map[5]];
  const float* lng1 = (const float*)d_in[map[6]];
  const float* lnb1 = (const float*)d_in[map[7]];
  const float* Win  = (const float*)d_in[map[8]];
  const float* Wine = (const float*)d_in[map[9]];
  const float* convW= (const float*)d_in[map[10]];
  const float* convB= (const float*)d_in[map[11]];
  const float* Wx   = (const float*)d_in[map[12]];
  const float* Wdt  = (const float*)d_in[map[13]];
  const float* bdt  = (const float*)d_in[map[14]];
  const float* Alog = (const float*)d_in[map[15]];
  const float* Dp   = (const float*)d_in[map[16]];
  const float* Wout = (const float*)d_in[map[17]];
  const float* bout = (const float*)d_in[map[18]];
  const float* Wfo  = (const float*)d_in[map[19]];
  const float* bfo  = (const float*)d_in[map[20]];

  float* ob = (float*)d_out;
  float* ws = (float*)d_ws;

  // pass-through outputs 2/3
  k_copy4<<<4096,256,0,stream>>>(s1, ob + 2*BLD);
  k_copy4<<<4096,256,0,stream>>>(s2, ob + 3*BLD);

  const size_t SCN512 = (size_t)BZ*512*DD*NN;   // 1,048,576
  const size_t SCN256 = (size_t)BZ*256*DD*NN;   // 524,288
  // layout (float units; bf16 buffers occupy half their slot)
  const size_t need512 = (10*BLD + 4*BML + 12*SCN512 + 64)*sizeof(float);
  const size_t need256 = (10*BLD + 4*BML + 12*SCN256 + 64)*sizeof(float);

  if (ws_size >= need256){
    const bool big = (ws_size >= need512);
    const size_t SC = big ? SCN512 : SCN256;
    float* X1  = ws;
    float* X2  = ws + 1*BLD;
    ushort_t* XBa = (ushort_t*)(ws + 2*BLD);
    ushort_t* ZBa = (ushort_t*)(ws + 3*BLD);
    ushort_t* XBb = (ushort_t*)(ws + 4*BLD);
    ushort_t* ZBb = (ushort_t*)(ws + 5*BLD);
    ushort_t* Y0  = (ushort_t*)(ws + 6*BLD);
    ushort_t* Y1  = (ushort_t*)(ws + 7*BLD);
    ushort_t* Y2  = (ushort_t*)(ws + 8*BLD);
    ushort_t* Y3  = (ushort_t*)(ws + 9*BLD);
    float* M00 = ws + 10*BLD;
    float* M01 = M00 + BML;
    float* M10 = M01 + BML;
    float* M11 = M10 + BML;
    float* PP  = M11 + BML;
    float* FF  = PP + 4*SC;
    float* HH  = FF + 4*SC;

    for (int pr=0; pr<2; ++pr){
      const int i0 = pr*2;
      if (pr==0)
        k_in2<<<1024,256,0,stream>>>(img1, s1, img2, s2, lng0,lnb0,lng1,lnb1,
                                     Win, Wine, Wx, 0, XBa,ZBa,XBb,ZBb, M00,M01,M10,M11);
      else
        k_in2<<<1024,256,0,stream>>>(X1, X2, X2, X1, lng0,lnb0,lng1,lnb1,
                                     Win, Wine, Wx, 2, XBa,ZBa,XBb,ZBb, M00,M01,M10,M11);
      if (big){
        k_scan4<512,false><<<4*BZ*512,64,0,stream>>>(XBa,XBb,ZBa,ZBb, Y0,Y1,Y2,Y3,
                                                     M00,M01,M10,M11, convW,convB,Wdt,bdt,Alog,Dp,
                                                     i0, PP,FF,HH);
        k_mid4<512><<<32,256,0,stream>>>(PP,FF,HH);
        k_scan4<512,true ><<<4*BZ*512,64,0,stream>>>(XBa,XBb,ZBa,ZBb, Y0,Y1,Y2,Y3,
                                                     M00,M01,M10,M11, convW,convB,Wdt,bdt,Alog,Dp,
                                                     i0, PP,FF,HH);
      } else {
        k_scan4<256,false><<<4*BZ*256,64,0,stream>>>(XBa,XBb,ZBa,ZBb, Y0,Y1,Y2,Y3,
                                                     M00,M01,M10,M11, convW,convB,Wdt,bdt,Alog,Dp,
                                                     i0, PP,FF,HH);
        k_mid4<256><<<32,256,0,stream>>>(PP,FF,HH);
        k_scan4<256,true ><<<4*BZ*256,64,0,stream>>>(XBa,XBb,ZBa,ZBb, Y0,Y1,Y2,Y3,
                                                     M00,M01,M10,M11, convW,convB,Wdt,bdt,Alog,Dp,
                                                     i0, PP,FF,HH);
      }
      if (pr==0)
        k_out2<<<512,256,0,stream>>>(Y0,Y1,Y2,Y3, img1,img2, Wout,bout, X1,X2);
      else
        k_tail<<<256,256,0,stream>>>(Y0,Y1,Y2,Y3, X1,X2, Wout,bout, Wfo,bfo, ob);
    }
    return;
  }

  // ---- fallback (R14 structure, f32) ----
  float* X1 = ws;
  float* X2 = ws + 1*BLD;
  float* FS = ws + 2*BLD;
  float* XB = ws + 3*BLD;
  float* ZB = ws + 4*BLD;
  float* YB = ws + 5*BLD;
  float* M0 = ws + 6*BLD;
  float* M1 = M0 + BML;
  float* PP = M1 + BML;
  float* FF = PP + SCN256;
  float* HH = FF + SCN256;

  const size_t need = (6*BLD + 2*BML + 3*SCN256 + 64)*sizeof(float);
  if (ws_size < need) return;

  const float* bx0[4] = {img1, img2, X1, X2};
  const float* bx1[4] = {s1,   s2,   X2, X1};

  for (int i=0; i<4; ++i){
    f_in<<<256,256,0,stream>>>(bx0[i], bx1[i], lng0, lnb0, lng1, lnb1,
                               Win, Wine, Wx, i, XB, ZB, M0, M1);
    for (int d=0; d<2; ++d){
      const int id = i*2+d;
      const float* Md = d ? M1 : M0;
      if (d==0){
        f_scan<0,false><<<BZ*256,64,0,stream>>>(XB,nullptr,nullptr,Md,convW,convB,Wdt,bdt,Alog,nullptr,id,PP,FF,nullptr);
        f_mid<<<8,256,0,stream>>>(PP,FF,HH);
        f_scan<0,true ><<<BZ*256,64,0,stream>>>(XB,ZB,YB,Md,convW,convB,Wdt,bdt,Alog,Dp,id,nullptr,nullptr,HH);
      } else {
        f_scan<1,false><<<BZ*256,64,0,stream>>>(XB,nullptr,nullptr,Md,convW,convB,Wdt,bdt,Alog,nullptr,id,PP,FF,nullptr);
        f_mid<<<8,256,0,stream>>>(PP,FF,HH);
        f_scan<1,true ><<<BZ*256,64,0,stream>>>(XB,ZB,YB,Md,convW,convB,Wdt,bdt,Alog,Dp,id,nullptr,nullptr,HH);
      }
    }
    const float* Wop = Wout + (size_t)i*DD*DD;
    const float* bop = bout + (size_t)i*DD;
    if      (i==0) f_out<0><<<256,256,0,stream>>>(YB, img1, Wop, bop, X1);
    else if (i==1) f_out<0><<<256,256,0,stream>>>(YB, img2, Wop, bop, X2);
    else if (i==2) f_out<0><<<256,256,0,stream>>>(YB, X1,   Wop, bop, FS);
    else           f_out<1><<<256,256,0,stream>>>(YB, X2,   Wop, bop, FS);
  }
  f_fuse<<<256,256,0,stream>>>(FS, X1, X2, Wfo, bfo, ob);
}